// Round 12
// baseline (322.089 us; speedup 1.0000x reference)
//
#include <hip/hip_runtime.h>

#define NROWS 8192
#define DDIM  256

typedef __attribute__((ext_vector_type(8))) short bf16x8;
typedef __attribute__((ext_vector_type(4))) float f32x4;

// round-to-nearest-even f32 -> bf16 bits (inputs are finite gaussians; no NaN path)
static __device__ __forceinline__ unsigned short f2bf(float f) {
    unsigned u = __float_as_uint(f);
    u += 0x7fff + ((u >> 16) & 1);
    return (unsigned short)(u >> 16);
}

// Pass 1: f32 -> bf16 + per-row sum of squares, writing FRAGMENT-MAJOR
// tiled layout: element (row, k) -> p*4096 + kc*128 + rr*8 + (k%8),
// p=row/16, rr=row%16, kc=k/8. An MFMA fragment load (p, chunk, rr) is then
// 64 lanes x 16B fully contiguous (1KB/wave) straight from global.
__global__ __launch_bounds__(256) void rbf_prep_kernel(
    const float* __restrict__ x, const float* __restrict__ y,
    unsigned short* __restrict__ xb, unsigned short* __restrict__ yb,
    float* __restrict__ xsq, float* __restrict__ ysq)
{
    const int lane = threadIdx.x & 63;
    const int wid  = threadIdx.x >> 6;
    int row = blockIdx.x * 4 + wid;            // 0..16383
    const float* src; unsigned short* dst; float* sq; int r;
    if (row < NROWS) { src = x; dst = xb; sq = xsq; r = row; }
    else             { src = y; dst = yb; sq = ysq; r = row - NROWS; }

    const float4 v = ((const float4*)(src + (size_t)r * DDIM))[lane];   // k = lane*4..lane*4+3
    ushort4 b;
    b.x = f2bf(v.x); b.y = f2bf(v.y); b.z = f2bf(v.z); b.w = f2bf(v.w);

    const int p  = r >> 4;
    const int rr = r & 15;
    // k = lane*4 -> kc = lane>>1, sub-offset (lane&1)*4
    const int eidx = p * 4096 + (lane >> 1) * 128 + rr * 8 + (lane & 1) * 4;
    *(ushort4*)(dst + eidx) = b;

    float s = v.x * v.x + v.y * v.y + v.z * v.z + v.w * v.w;
    #pragma unroll
    for (int o = 32; o > 0; o >>= 1) s += __shfl_down(s, o);
    if (lane == 0) sq[r] = s;
}

// Pass 2: C = Xb * Yb^T via bf16 MFMA, epilogue exp(-(xsq + ysq - 2C)).
// NO LDS, NO BARRIERS: inputs (8MB bf16) are L2/L3-resident; fragments are
// loaded register-direct from the tiled layout (coalesced 1KB/wave loads).
// Removes the stage->drain->MFMA phase serialization that held R6 at ~2x
// the 42us store floor (common-mistake #7: don't LDS-stage L2-fit data).
// Waves run fully independent -> continuous nt-store stream.
__global__ __launch_bounds__(256) void rbf_gemm_kernel(
    const unsigned short* __restrict__ A,   // tiled Xb
    const unsigned short* __restrict__ B,   // tiled Yb
    const float* __restrict__ xsq, const float* __restrict__ ysq,
    float* __restrict__ out)
{
    const int t    = threadIdx.x;
    const int lane = t & 63;
    const int wid  = t >> 6;
    const int wr   = wid >> 1;          // wave row (0..1) -> 64-row slab of X
    const int wc   = wid & 1;           // wave col (0..1) -> 64-col slab of Y
    const int brow = blockIdx.y * 128;
    const int bcol = blockIdx.x * 128;

    const int rr = lane & 15;
    const int kq = lane >> 4;

    // fragment base: panel (brow/16 + wr*4 + m), chunk (ks*4 + kq), row rr
    const unsigned short* Ab = A + (size_t)((brow >> 4) + wr * 4) * 4096 + kq * 128 + rr * 8;
    const unsigned short* Bb = B + (size_t)((bcol >> 4) + wc * 4) * 4096 + kq * 128 + rr * 8;

    f32x4 acc[4][4] = {};               // [m][n] transposed 16x16 fragments

    // register double-buffer, prefetch depth 1; full unroll => static indices
    bf16x8 a[2][4], b[2][4];
    #pragma unroll
    for (int m = 0; m < 4; ++m) {
        a[0][m] = *(const bf16x8*)(Ab + m * 4096);
        b[0][m] = *(const bf16x8*)(Bb + m * 4096);
    }
    #pragma unroll
    for (int ks = 0; ks < 8; ++ks) {
        const int cur = ks & 1, nxt = cur ^ 1;
        if (ks < 7) {
            #pragma unroll
            for (int m = 0; m < 4; ++m) {
                a[nxt][m] = *(const bf16x8*)(Ab + m * 4096 + (ks + 1) * 512);
                b[nxt][m] = *(const bf16x8*)(Bb + m * 4096 + (ks + 1) * 512);
            }
        }
        #pragma unroll
        for (int m = 0; m < 4; ++m)
            #pragma unroll
            for (int n = 0; n < 4; ++n)
                acc[m][n] = __builtin_amdgcn_mfma_f32_16x16x32_bf16(b[cur][n], a[cur][m], acc[m][n], 0, 0, 0);
    }

    // epilogue: swapped-operand fragment => lane's X row = lane&15,
    // Y cols = (lane>>4)*4 + {0..3} -> nontemporal f32x4 stores
    const int cl = lane & 15;
    const int rq = lane >> 4;
    #pragma unroll
    for (int m = 0; m < 4; ++m) {
        const int row = brow + wr * 64 + m * 16 + cl;
        const float xsv = xsq[row];
        float* orow = out + (size_t)row * NROWS;
        #pragma unroll
        for (int n = 0; n < 4; ++n) {
            const int col = bcol + wc * 64 + n * 16 + rq * 4;
            const float4 ysv = *(const float4*)(ysq + col);
            f32x4 o;
            o[0] = __expf(-fmaxf(xsv + ysv.x - 2.0f * acc[m][n][0], 0.0f));
            o[1] = __expf(-fmaxf(xsv + ysv.y - 2.0f * acc[m][n][1], 0.0f));
            o[2] = __expf(-fmaxf(xsv + ysv.z - 2.0f * acc[m][n][2], 0.0f));
            o[3] = __expf(-fmaxf(xsv + ysv.w - 2.0f * acc[m][n][3], 0.0f));
            __builtin_nontemporal_store(o, (f32x4*)(orow + col));
        }
    }
}

extern "C" void kernel_launch(void* const* d_in, const int* in_sizes, int n_in,
                              void* d_out, int out_size, void* d_ws, size_t ws_size,
                              hipStream_t stream) {
    const float* x = (const float*)d_in[0];
    const float* y = (const float*)d_in[1];
    float* out = (float*)d_out;

    // ws layout: xb (4 MiB tiled) | yb (4 MiB tiled) | xsq (32 KiB) | ysq (32 KiB)
    unsigned short* xb = (unsigned short*)d_ws;
    unsigned short* yb = xb + (size_t)NROWS * DDIM;
    float* xsq = (float*)(yb + (size_t)NROWS * DDIM);
    float* ysq = xsq + NROWS;

    rbf_prep_kernel<<<dim3((2 * NROWS) / 4), 256, 0, stream>>>(x, y, xb, yb, xsq, ysq);
    rbf_gemm_kernel<<<dim3(NROWS / 128, NROWS / 128), 256, 0, stream>>>(xb, yb, xsq, ysq, out);
}